// Round 12
// baseline (182.853 us; speedup 1.0000x reference)
//
#include <hip/hip_runtime.h>
#include <math.h>

// N = 20000, E = 640000, IN_DIM = HID = 128, OUT = 64
// Activations bf16 (ushort bits), accumulation fp32 via MFMA 16x16x32.
// Padded-CSR design: ONE atomic pass builds col[N][CAP]; deg lives in cnt.
// Round-5:  atomics execute at the coherent point (~20 MB write-through/pass
//           over E) -> run exactly one atomic pass.
// Round-9:  do NOT L2-block the gathers; the 5 MB array is IC-resident and
//           blocking forced 8x replicated L2 fills (+40us).
// Round-10: aggs are BW-bound (~4 TB/s random gather) -- unroll was neutral.
//           Fill is atomic-LATENCY-bound -> batch the atomics (this round).

#define CAP 96   // max supported degree; E/N=32 mean, expected max ~57, P(>96)~e^-41

typedef __attribute__((ext_vector_type(8))) short short8;
typedef __attribute__((ext_vector_type(4))) float floatx4;

__device__ __forceinline__ unsigned short f2b(float f) {
    unsigned u = __float_as_uint(f);
    unsigned r = (u + 0x7fffu + ((u >> 16) & 1u)) >> 16;
    return (unsigned short)r;
}
__device__ __forceinline__ float b2f(unsigned short h) {
    return __uint_as_float(((unsigned)h) << 16);
}
__device__ __forceinline__ float b2f_lo(unsigned v) {
    return __uint_as_float(v << 16);
}
__device__ __forceinline__ float b2f_hi(unsigned v) {
    return __uint_as_float(v & 0xffff0000u);
}
__device__ __forceinline__ floatx4 MFMA(short8 a, short8 b, floatx4 c) {
    return __builtin_amdgcn_mfma_f32_16x16x32_bf16(a, b, c, 0, 0, 0);
}
__device__ __forceinline__ float gelu_exact(float x) {
    return 0.5f * x * (1.0f + erff(x * 0.70710678118654752440f));
}

// B fragment for (ct, ks) at lane: packed W layout
#define FRAG(P, ct, ks, lane) (*(const short8*)((P) + (((((ct)*4 + (ks))*64) + (lane)) << 3)))

// accumulate one gathered row (16B slice per lane) into acc[8]
#define ACC_Q(q, sc) do { \
    acc[0] = fmaf(b2f_lo((q).x), (sc), acc[0]); \
    acc[1] = fmaf(b2f_hi((q).x), (sc), acc[1]); \
    acc[2] = fmaf(b2f_lo((q).y), (sc), acc[2]); \
    acc[3] = fmaf(b2f_hi((q).y), (sc), acc[3]); \
    acc[4] = fmaf(b2f_lo((q).z), (sc), acc[4]); \
    acc[5] = fmaf(b2f_hi((q).z), (sc), acc[5]); \
    acc[6] = fmaf(b2f_lo((q).w), (sc), acc[6]); \
    acc[7] = fmaf(b2f_hi((q).w), (sc), acc[7]); \
} while (0)

#define ACC_Q1(q) do { \
    acc[0] += b2f_lo((q).x); acc[1] += b2f_hi((q).x); \
    acc[2] += b2f_lo((q).y); acc[3] += b2f_hi((q).y); \
    acc[4] += b2f_lo((q).z); acc[5] += b2f_hi((q).z); \
    acc[6] += b2f_lo((q).w); acc[7] += b2f_hi((q).w); \
} while (0)

// ---------------- weight packing + cnt zeroing (44 blocks) ----------------

__global__ __launch_bounds__(256) void pack_zero_kernel(
    int* __restrict__ cnt, int N,
    const float* Wg, const float* Wsl, const float* Wsr,
    const float* W1, const float* W2, const float* W3,
    unsigned short* Pg, unsigned short* Psl, unsigned short* Psr,
    unsigned short* P1, unsigned short* P2, unsigned short* P3)
{
    int t = blockIdx.x * 256 + threadIdx.x;
    for (int i = t; i < N; i += 11264) cnt[i] = 0;
    const float* W; unsigned short* P; int NC = 128; int base;
    if (t < 2048)       { W = Wg;  P = Pg;  base = t; }
    else if (t < 4096)  { W = Wsl; P = Psl; base = t - 2048; }
    else if (t < 6144)  { W = Wsr; P = Psr; base = t - 4096; }
    else if (t < 8192)  { W = W1;  P = P1;  base = t - 6144; }
    else if (t < 10240) { W = W2;  P = P2;  base = t - 8192; }
    else if (t < 11264) { W = W3;  P = P3;  base = t - 10240; NC = 64; }
    else return;
    int l  = base & 63;
    int ks = (base >> 6) & 3;
    int ct = base >> 8;
    int n  = ct * 16 + (l & 15);
    int k0 = ks * 32 + ((l >> 4) << 3);
    short8 v;
    #pragma unroll
    for (int j = 0; j < 8; j++) v[j] = (short)f2b(W[(size_t)(k0 + j) * NC + n]);
    *(short8*)(P + ((size_t)base << 3)) = v;
}

// ---------------- fill (padded CSR, batched atomics) + GCN GEMM ------------
// XCD-partitioned scatter (round-4/5 win): block b = (chunk b>>3, partition
// b&7). Round-11: 3-phase batched body -- (1) load dst/src + predicates,
// (2) issue all matching atomicAdds back-to-back (independent, in flight
// together), (3) guarded col stores. Rank order is arbitrary -> semantics
// preserved. All arrays statically indexed (no scratch).

__global__ __launch_bounds__(256) void fill_gemm_kernel(
    const int* __restrict__ eidx, int E,
    int* __restrict__ cnt, int* __restrict__ col,
    const float* __restrict__ feat,
    const unsigned short* __restrict__ Pg,
    unsigned short* __restrict__ xs, int M, int fillBlocks, int PS)
{
    if ((int)blockIdx.x < fillBlocks) {
        int chunk = blockIdx.x >> 3;
        int p = blockIdx.x & 7;
        int lo = p * PS;
        int hi = lo + PS;
        int e0 = chunk * 2048;
        int e1 = e0 + 2048 < E ? e0 + 2048 : E;
        int base = e0 + (int)threadIdx.x;

        int  d[8]; int s[8]; bool m[8]; int r[8];
        // phase 1: load + predicate
        #pragma unroll
        for (int i = 0; i < 8; i++) {
            int e = base + i * 256;
            m[i] = false; d[i] = 0; s[i] = 0; r[i] = CAP;
            if (e < e1) {
                int dd = eidx[E + e];
                if (dd >= lo && dd < hi) {
                    m[i] = true; d[i] = dd; s[i] = eidx[e];
                }
            }
        }
        // phase 2: issue all atomics (independent -> overlapped latency)
        #pragma unroll
        for (int i = 0; i < 8; i++)
            if (m[i]) r[i] = atomicAdd(&cnt[d[i]], 1);
        // phase 3: guarded stores
        #pragma unroll
        for (int i = 0; i < 8; i++)
            if (m[i] && r[i] < CAP) col[d[i] * CAP + r[i]] = s[i];
        return;
    }
    // GCN GEMM: wave computes 16 rows x 64 cols of xs = bf16(feat @ Wg)
    int bid = blockIdx.x - fillBlocks;
    int w = bid * 4 + (threadIdx.x >> 6);
    if (w >= (M / 16) * 2) return;
    int lane = threadIdx.x & 63;
    int m = lane & 15, quad = lane >> 4;
    int rt = w >> 1, ch = w & 1;
    const float* arow = feat + (size_t)(rt * 16 + m) * 128;
    short8 a[4];
    #pragma unroll
    for (int ks = 0; ks < 4; ks++) {
        float4 f0 = *(const float4*)(arow + ks * 32 + quad * 8);
        float4 f1 = *(const float4*)(arow + ks * 32 + quad * 8 + 4);
        short8 s;
        s[0] = (short)f2b(f0.x); s[1] = (short)f2b(f0.y);
        s[2] = (short)f2b(f0.z); s[3] = (short)f2b(f0.w);
        s[4] = (short)f2b(f1.x); s[5] = (short)f2b(f1.y);
        s[6] = (short)f2b(f1.z); s[7] = (short)f2b(f1.w);
        a[ks] = s;
    }
    #pragma unroll
    for (int ct = 0; ct < 4; ct++) {
        floatx4 acc = {0.f, 0.f, 0.f, 0.f};
        #pragma unroll
        for (int ks = 0; ks < 4; ks++)
            acc = MFMA(a[ks], FRAG(Pg, ch * 4 + ct, ks, lane), acc);
        #pragma unroll
        for (int reg = 0; reg < 4; reg++)
            xs[(size_t)(rt * 16 + quad * 4 + reg) * 128 + (ch * 4 + ct) * 16 + m] =
                f2b(acc[reg]);
    }
}

// ---------------- GCN aggregation (unblocked; XCD-aligned rows) ------------
// h1[d] = relu(dinv_d*(sum_s dinv_s*xs[s] + dinv_d*xs[d]) + b)
// Row->XCD alignment: rows of partition p were col-written by XCD p during
// fill; bijective swizzle bid=(B&7)*(grid/8)+(B>>3) puts their agg blocks
// on the same XCD so col/cnt reads are L2-local (guard: grid%8==0).

__global__ __launch_bounds__(256) void agg_gcn_kernel(
    const unsigned short* __restrict__ X, const int* __restrict__ cnt,
    const int* __restrict__ col, const float* __restrict__ bias,
    unsigned short* __restrict__ Y, int N)
{
    int B = (int)blockIdx.x;
    int bid = ((gridDim.x & 7) == 0) ? (B & 7) * ((int)gridDim.x >> 3) + (B >> 3) : B;
    int w = bid * 4 + ((int)threadIdx.x >> 6);
    if (w >= N) return;
    int lane = threadIdx.x & 63;
    int g = lane >> 4, t = lane & 15;
    const uint4* Xq = (const uint4*)X;

    int deg = cnt[w];
    int n = deg < CAP ? deg : CAP;
    int beg = w * CAP, end = beg + n;

    float acc[8] = {0.f, 0.f, 0.f, 0.f, 0.f, 0.f, 0.f, 0.f};

    int e = beg + g;
    for (; e + 12 < end; e += 16) {
        int s0 = col[e];
        int s1 = col[e + 4];
        int s2 = col[e + 8];
        int s3 = col[e + 12];
        float sc0 = rsqrtf((float)(cnt[s0] + 1));
        float sc1 = rsqrtf((float)(cnt[s1] + 1));
        float sc2 = rsqrtf((float)(cnt[s2] + 1));
        float sc3 = rsqrtf((float)(cnt[s3] + 1));
        uint4 q0 = Xq[(size_t)s0 * 16 + t];
        uint4 q1 = Xq[(size_t)s1 * 16 + t];
        uint4 q2 = Xq[(size_t)s2 * 16 + t];
        uint4 q3 = Xq[(size_t)s3 * 16 + t];
        ACC_Q(q0, sc0);
        ACC_Q(q1, sc1);
        ACC_Q(q2, sc2);
        ACC_Q(q3, sc3);
    }
    for (; e < end; e += 4) {
        int s0 = col[e];
        float sc0 = rsqrtf((float)(cnt[s0] + 1));
        uint4 q0 = Xq[(size_t)s0 * 16 + t];
        ACC_Q(q0, sc0);
    }

    #pragma unroll
    for (int i = 0; i < 8; i++) {
        acc[i] += __shfl_xor(acc[i], 16);
        acc[i] += __shfl_xor(acc[i], 32);
    }
    if (g == 0) {
        float dw = rsqrtf((float)(deg + 1));
        uint4 q = Xq[(size_t)w * 16 + t];  // self loop
        ACC_Q(q, dw);
        float4 b0 = *(const float4*)(bias + t * 8);
        float4 b1 = *(const float4*)(bias + t * 8 + 4);
        float out[8];
        out[0] = fmaxf(fmaf(acc[0], dw, b0.x), 0.f);
        out[1] = fmaxf(fmaf(acc[1], dw, b0.y), 0.f);
        out[2] = fmaxf(fmaf(acc[2], dw, b0.z), 0.f);
        out[3] = fmaxf(fmaf(acc[3], dw, b0.w), 0.f);
        out[4] = fmaxf(fmaf(acc[4], dw, b1.x), 0.f);
        out[5] = fmaxf(fmaf(acc[5], dw, b1.y), 0.f);
        out[6] = fmaxf(fmaf(acc[6], dw, b1.z), 0.f);
        out[7] = fmaxf(fmaf(acc[7], dw, b1.w), 0.f);
        uint4 r;
        r.x = (unsigned)f2b(out[0]) | ((unsigned)f2b(out[1]) << 16);
        r.y = (unsigned)f2b(out[2]) | ((unsigned)f2b(out[3]) << 16);
        r.z = (unsigned)f2b(out[4]) | ((unsigned)f2b(out[5]) << 16);
        r.w = (unsigned)f2b(out[6]) | ((unsigned)f2b(out[7]) << 16);
        ((uint4*)Y)[(size_t)w * 16 + t] = r;
    }
}

// ---------------- fused SAGE-mean + SAGE layer + MLP + value head ----------
// One block per 16-row tile. Phase A: wave widx mean-aggregates rows
// widx*4..+3 of h1 into LDS zm (bf16), unblocked unroll-4 gather.
// Phase B: 4 waves cooperate on the tile's MLP (2 of 8 ct-tiles each per
// 128-col layer, 1 of 4 in layer 3), ping-ponging zm <-> za with barriers.

__global__ __launch_bounds__(256) void sage_fused_kernel(
    const unsigned short* __restrict__ h1, const int* __restrict__ cnt,
    const int* __restrict__ col,
    const unsigned short* __restrict__ Psl, const unsigned short* __restrict__ Psr,
    const float* __restrict__ bsl,
    const unsigned short* __restrict__ P1, const float* __restrict__ b1,
    const unsigned short* __restrict__ P2, const float* __restrict__ b2,
    const unsigned short* __restrict__ P3, const float* __restrict__ b3,
    const float* __restrict__ Wv, const float* __restrict__ bv,
    float* __restrict__ means, float* __restrict__ values, int N)
{
    __shared__ unsigned short zm[16 * 136];   // mean, later z1
    __shared__ unsigned short za[16 * 136];   // h2, later z2
    __shared__ float vp[16][4];               // value partials [row][wave]
    int widx = threadIdx.x >> 6, lane = threadIdx.x & 63;
    int r0 = blockIdx.x * 16;
    if (r0 >= N) return;
    int g = lane >> 4, t = lane & 15;
    const uint4* Xq = (const uint4*)h1;

    // ---- phase A: mean aggregation, wave widx -> rows widx*4 .. +3 ----
    for (int rr = 0; rr < 4; rr++) {
        int w = r0 + widx * 4 + rr;
        int deg = cnt[w];
        int n = deg < CAP ? deg : CAP;
        int beg = w * CAP, end = beg + n;
        float acc[8] = {0.f, 0.f, 0.f, 0.f, 0.f, 0.f, 0.f, 0.f};
        int e = beg + g;
        for (; e + 12 < end; e += 16) {
            int s0 = col[e];
            int s1 = col[e + 4];
            int s2 = col[e + 8];
            int s3 = col[e + 12];
            uint4 q0 = Xq[(size_t)s0 * 16 + t];
            uint4 q1 = Xq[(size_t)s1 * 16 + t];
            uint4 q2 = Xq[(size_t)s2 * 16 + t];
            uint4 q3 = Xq[(size_t)s3 * 16 + t];
            ACC_Q1(q0);
            ACC_Q1(q1);
            ACC_Q1(q2);
            ACC_Q1(q3);
        }
        for (; e < end; e += 4) {
            int s0 = col[e];
            uint4 q0 = Xq[(size_t)s0 * 16 + t];
            ACC_Q1(q0);
        }
        #pragma unroll
        for (int i = 0; i < 8; i++) {
            acc[i] += __shfl_xor(acc[i], 16);
            acc[i] += __shfl_xor(acc[i], 32);
        }
        if (g == 0) {
            float rc = 1.0f / (float)(deg > 0 ? deg : 1);
            uint4 r;
            r.x = (unsigned)f2b(acc[0] * rc) | ((unsigned)f2b(acc[1] * rc) << 16);
            r.y = (unsigned)f2b(acc[2] * rc) | ((unsigned)f2b(acc[3] * rc) << 16);
            r.z = (unsigned)f2b(acc[4] * rc) | ((unsigned)f2b(acc[5] * rc) << 16);
            r.w = (unsigned)f2b(acc[6] * rc) | ((unsigned)f2b(acc[7] * rc) << 16);
            *(uint4*)(zm + (widx * 4 + rr) * 136 + t * 8) = r;
        }
    }
    __syncthreads();   // B1: zm (mean) complete

    int m = t, quad = g;

    // A fragments: mean from LDS, root h1 from global
    short8 am[4], ar[4];
    #pragma unroll
    for (int ks = 0; ks < 4; ks++) {
        am[ks] = *(const short8*)(zm + m * 136 + ks * 32 + quad * 8);
        ar[ks] = *(const short8*)(h1 + (size_t)(r0 + m) * 128 + ks * 32 + quad * 8);
    }

    // SAGE layer: wave widx -> ct = 2*widx, 2*widx+1; h2 -> za; value partials
    float vpart[4] = {0.f, 0.f, 0.f, 0.f};
    #pragma unroll
    for (int ci = 0; ci < 2; ci++) {
        int ct = widx * 2 + ci;
        floatx4 acc = {0.f, 0.f, 0.f, 0.f};
        #pragma unroll
        for (int ks = 0; ks < 4; ks++) acc = MFMA(am[ks], FRAG(Psl, ct, ks, lane), acc);
        #pragma unroll
        for (int ks = 0; ks < 4; ks++) acc = MFMA(ar[ks], FRAG(Psr, ct, ks, lane), acc);
        float bb = bsl[ct * 16 + m];
        float wvv = Wv[ct * 16 + m];
        #pragma unroll
        for (int reg = 0; reg < 4; reg++) {
            float o = fmaxf(acc[reg] + bb, 0.f);
            vpart[reg] = fmaf(o, wvv, vpart[reg]);
            za[(quad * 4 + reg) * 136 + ct * 16 + m] = f2b(o);
        }
    }
    #pragma unroll
    for (int off = 1; off <= 8; off <<= 1) {
        #pragma unroll
        for (int reg = 0; reg < 4; reg++)
            vpart[reg] += __shfl_xor(vpart[reg], off);
    }
    if (m == 0) {
        #pragma unroll
        for (int reg = 0; reg < 4; reg++)
            vp[quad * 4 + reg][widx] = vpart[reg];
    }
    __syncthreads();   // B2: za (h2), vp complete

    if (threadIdx.x < 16) {
        float v = vp[threadIdx.x][0] + vp[threadIdx.x][1]
                + vp[threadIdx.x][2] + vp[threadIdx.x][3];
        values[r0 + threadIdx.x] = v + bv[0];
    }

    // layer 1: za -> zm
    short8 a1[4];
    #pragma unroll
    for (int ks = 0; ks < 4; ks++)
        a1[ks] = *(const short8*)(za + m * 136 + ks * 32 + quad * 8);
    #pragma unroll
    for (int ci = 0; ci < 2; ci++) {
        int ct = widx * 2 + ci;
        floatx4 acc = {0.f, 0.f, 0.f, 0.f};
        #pragma unroll
        for (int ks = 0; ks < 4; ks++) acc = MFMA(a1[ks], FRAG(P1, ct, ks, lane), acc);
        float bb = b1[ct * 16 + m];
        #pragma unroll
        for (int reg = 0; reg < 4; reg++)
            zm[(quad * 4 + reg) * 136 + ct * 16 + m] = f2b(gelu_exact(acc[reg] + bb));
    }
    __syncthreads();   // B3: zm (z1) complete

    // layer 2: zm -> za
    short8 a2[4];
    #pragma unroll
    for (int ks = 0; ks < 4; ks++)
        a2[ks] = *(const short8*)(zm + m * 136 + ks * 32 + quad * 8);
    #pragma unroll
    for (int ci = 0; ci < 2; ci++) {
        int ct = widx * 2 + ci;
        floatx4 acc = {0.f, 0.f, 0.f, 0.f};
        #pragma unroll
        for (int ks = 0; ks < 4; ks++) acc = MFMA(a2[ks], FRAG(P2, ct, ks, lane), acc);
        float bb = b2[ct * 16 + m];
        #pragma unroll
        for (int reg = 0; reg < 4; reg++)
            za[(quad * 4 + reg) * 136 + ct * 16 + m] = f2b(gelu_exact(acc[reg] + bb));
    }
    __syncthreads();   // B4: za (z2) complete

    // layer 3 (64 cols): wave widx -> ct = widx; za -> means (global)
    short8 a3[4];
    #pragma unroll
    for (int ks = 0; ks < 4; ks++)
        a3[ks] = *(const short8*)(za + m * 136 + ks * 32 + quad * 8);
    {
        int ct = widx;
        floatx4 acc = {0.f, 0.f, 0.f, 0.f};
        #pragma unroll
        for (int ks = 0; ks < 4; ks++) acc = MFMA(a3[ks], FRAG(P3, ct, ks, lane), acc);
        float bb = b3[ct * 16 + m];
        #pragma unroll
        for (int reg = 0; reg < 4; reg++)
            means[(size_t)(r0 + quad * 4 + reg) * 64 + ct * 16 + m] = acc[reg] + bb;
    }
}

// ---------------- launch ----------------

extern "C" void kernel_launch(void* const* d_in, const int* in_sizes, int n_in,
                              void* d_out, int out_size, void* d_ws, size_t ws_size,
                              hipStream_t stream) {
    const float* feat  = (const float*)d_in[0];
    const int*   eidx  = (const int*)d_in[1];
    const float* W_gcn = (const float*)d_in[2];
    const float* b_gcn = (const float*)d_in[3];
    const float* W_sl  = (const float*)d_in[4];
    const float* b_sl  = (const float*)d_in[5];
    const float* W_sr  = (const float*)d_in[6];
    const float* W1    = (const float*)d_in[7];
    const float* b1    = (const float*)d_in[8];
    const float* W2    = (const float*)d_in[9];
    const float* b2    = (const float*)d_in[10];
    const float* W3    = (const float*)d_in[11];
    const float* b3    = (const float*)d_in[12];
    const float* Wv    = (const float*)d_in[13];
    const float* bv    = (const float*)d_in[14];

    const int N = in_sizes[0] / 128;
    const int E = in_sizes[1] / 2;

    char* ws = (char*)d_ws;
    size_t off = 0;
    auto alloc = [&](size_t bytes) -> void* {
        void* p = ws + off;
        off += (bytes + 255) & ~(size_t)255;
        return p;
    };
    int*   cnt = (int*)alloc((size_t)N * 4);
    int*   col = (int*)alloc((size_t)N * CAP * 4);         // padded CSR, 7.68 MB
    unsigned short* xs   = (unsigned short*)alloc((size_t)N * 128 * 2);
    unsigned short* h1   = (unsigned short*)alloc((size_t)N * 128 * 2);
    unsigned short* Pg   = (unsigned short*)alloc(2048 * 8 * 2);
    unsigned short* Psl  = (unsigned short*)alloc(2048 * 8 * 2);
    unsigned short* Psr  = (unsigned short*)alloc(2048 * 8 * 2);
    unsigned short* P1   = (unsigned short*)alloc(2048 * 8 * 2);
    unsigned short* P2   = (unsigned short*)alloc(2048 * 8 * 2);
    unsigned short* P3   = (unsigned short*)alloc(1024 * 8 * 2);

    // 1: pack weights + zero cnt
    pack_zero_kernel<<<44, 256, 0, stream>>>(
        cnt, N, W_gcn, W_sl, W_sr, W1, W2, W3,
        Pg, Psl, Psr, P1, P2, P3);

    // 2: padded-CSR fill (batched atomics, XCD-partitioned) + GCN GEMM
    const int PS = (N + 7) / 8;                            // 2500 rows / partition
    const int fillBlocks = ((E + 2047) / 2048) * 8;        // 313 chunks x 8 = 2504
    const int gemmBlocks = ((N / 16) * 2 + 3) / 4;         // 625
    fill_gemm_kernel<<<fillBlocks + gemmBlocks, 256, 0, stream>>>(
        eidx, E, cnt, col, feat, Pg, xs, N, fillBlocks, PS);

    // 3: GCN aggregation (unblocked, XCD-aligned rows)
    const int agrid = (N + 3) / 4;                         // 5000 (= 8*625)
    agg_gcn_kernel<<<agrid, 256, 0, stream>>>(xs, cnt, col, b_gcn, h1, N);

    // 4: fused SAGE mean + SAGE layer + MLP + value head
    sage_fused_kernel<<<(N + 15) / 16, 256, 0, stream>>>(
        h1, cnt, col, Psl, Psr, b_sl, P1, b1, P2, b2, P3, b3, Wv, bv,
        (float*)d_out, (float*)d_out + (size_t)N * 64, N);
}

// Round 13
// 180.271 us; speedup vs baseline: 1.0143x; 1.0143x over previous
//
#include <hip/hip_runtime.h>
#include <math.h>

// N = 20000, E = 640000, IN_DIM = HID = 128, OUT = 64
// Activations bf16 (ushort bits), accumulation fp32 via MFMA 16x16x32.
// Padded-CSR design: ONE atomic pass builds col[N][CAP]; deg lives in cnt.
// Round-5:  atomics execute at the coherent point -> exactly one atomic pass.
// Round-9:  do NOT L2-block the gathers (IC-resident; blocking cost +40us).
// Round-10: aggs are BW-bound (~4 TB/s random gather) -- unroll neutral.
// Round-12: fill atomics are THROUGHPUT-bound at the coherent point --
//           batching them regressed (+5us). Simple strided loop is the floor.

#define CAP 96   // max supported degree; E/N=32 mean, expected max ~57, P(>96)~e^-41

typedef __attribute__((ext_vector_type(8))) short short8;
typedef __attribute__((ext_vector_type(4))) float floatx4;

__device__ __forceinline__ unsigned short f2b(float f) {
    unsigned u = __float_as_uint(f);
    unsigned r = (u + 0x7fffu + ((u >> 16) & 1u)) >> 16;
    return (unsigned short)r;
}
__device__ __forceinline__ float b2f(unsigned short h) {
    return __uint_as_float(((unsigned)h) << 16);
}
__device__ __forceinline__ float b2f_lo(unsigned v) {
    return __uint_as_float(v << 16);
}
__device__ __forceinline__ float b2f_hi(unsigned v) {
    return __uint_as_float(v & 0xffff0000u);
}
__device__ __forceinline__ floatx4 MFMA(short8 a, short8 b, floatx4 c) {
    return __builtin_amdgcn_mfma_f32_16x16x32_bf16(a, b, c, 0, 0, 0);
}
__device__ __forceinline__ float gelu_exact(float x) {
    return 0.5f * x * (1.0f + erff(x * 0.70710678118654752440f));
}

// B fragment for (ct, ks) at lane: packed W layout
#define FRAG(P, ct, ks, lane) (*(const short8*)((P) + (((((ct)*4 + (ks))*64) + (lane)) << 3)))

// accumulate one gathered row (16B slice per lane) into acc[8]
#define ACC_Q(q, sc) do { \
    acc[0] = fmaf(b2f_lo((q).x), (sc), acc[0]); \
    acc[1] = fmaf(b2f_hi((q).x), (sc), acc[1]); \
    acc[2] = fmaf(b2f_lo((q).y), (sc), acc[2]); \
    acc[3] = fmaf(b2f_hi((q).y), (sc), acc[3]); \
    acc[4] = fmaf(b2f_lo((q).z), (sc), acc[4]); \
    acc[5] = fmaf(b2f_hi((q).z), (sc), acc[5]); \
    acc[6] = fmaf(b2f_lo((q).w), (sc), acc[6]); \
    acc[7] = fmaf(b2f_hi((q).w), (sc), acc[7]); \
} while (0)

#define ACC_Q1(q) do { \
    acc[0] += b2f_lo((q).x); acc[1] += b2f_hi((q).x); \
    acc[2] += b2f_lo((q).y); acc[3] += b2f_hi((q).y); \
    acc[4] += b2f_lo((q).z); acc[5] += b2f_hi((q).z); \
    acc[6] += b2f_lo((q).w); acc[7] += b2f_hi((q).w); \
} while (0)

// ---------------- weight packing + cnt zeroing (44 blocks) ----------------

__global__ __launch_bounds__(256) void pack_zero_kernel(
    int* __restrict__ cnt, int N,
    const float* Wg, const float* Wsl, const float* Wsr,
    const float* W1, const float* W2, const float* W3,
    unsigned short* Pg, unsigned short* Psl, unsigned short* Psr,
    unsigned short* P1, unsigned short* P2, unsigned short* P3)
{
    int t = blockIdx.x * 256 + threadIdx.x;
    for (int i = t; i < N; i += 11264) cnt[i] = 0;
    const float* W; unsigned short* P; int NC = 128; int base;
    if (t < 2048)       { W = Wg;  P = Pg;  base = t; }
    else if (t < 4096)  { W = Wsl; P = Psl; base = t - 2048; }
    else if (t < 6144)  { W = Wsr; P = Psr; base = t - 4096; }
    else if (t < 8192)  { W = W1;  P = P1;  base = t - 6144; }
    else if (t < 10240) { W = W2;  P = P2;  base = t - 8192; }
    else if (t < 11264) { W = W3;  P = P3;  base = t - 10240; NC = 64; }
    else return;
    int l  = base & 63;
    int ks = (base >> 6) & 3;
    int ct = base >> 8;
    int n  = ct * 16 + (l & 15);
    int k0 = ks * 32 + ((l >> 4) << 3);
    short8 v;
    #pragma unroll
    for (int j = 0; j < 8; j++) v[j] = (short)f2b(W[(size_t)(k0 + j) * NC + n]);
    *(short8*)(P + ((size_t)base << 3)) = v;
}

// ---------------- fill (padded CSR, ONE atomic pass) + GCN GEMM ------------
// XCD-partitioned scatter (round-4/5 win): block b = (chunk b>>3, partition
// b&7). Simple strided loop (round-12: batching atomics regressed).
// GEMM (unscaled xs) is independent of cnt -> fused, overlaps scatter.

__global__ __launch_bounds__(256) void fill_gemm_kernel(
    const int* __restrict__ eidx, int E,
    int* __restrict__ cnt, int* __restrict__ col,
    const float* __restrict__ feat,
    const unsigned short* __restrict__ Pg,
    unsigned short* __restrict__ xs, int M, int fillBlocks, int PS)
{
    if ((int)blockIdx.x < fillBlocks) {
        int chunk = blockIdx.x >> 3;
        int p = blockIdx.x & 7;
        int lo = p * PS;
        int hi = lo + PS;
        int e0 = chunk * 2048;
        int e1 = e0 + 2048 < E ? e0 + 2048 : E;
        for (int e = e0 + (int)threadIdx.x; e < e1; e += 256) {
            int d = eidx[E + e];
            if (d >= lo && d < hi) {
                int r = atomicAdd(&cnt[d], 1);
                if (r < CAP) col[d * CAP + r] = eidx[e];
            }
        }
        return;
    }
    // GCN GEMM: wave computes 16 rows x 64 cols of xs = bf16(feat @ Wg)
    int bid = blockIdx.x - fillBlocks;
    int w = bid * 4 + (threadIdx.x >> 6);
    if (w >= (M / 16) * 2) return;
    int lane = threadIdx.x & 63;
    int m = lane & 15, quad = lane >> 4;
    int rt = w >> 1, ch = w & 1;
    const float* arow = feat + (size_t)(rt * 16 + m) * 128;
    short8 a[4];
    #pragma unroll
    for (int ks = 0; ks < 4; ks++) {
        float4 f0 = *(const float4*)(arow + ks * 32 + quad * 8);
        float4 f1 = *(const float4*)(arow + ks * 32 + quad * 8 + 4);
        short8 s;
        s[0] = (short)f2b(f0.x); s[1] = (short)f2b(f0.y);
        s[2] = (short)f2b(f0.z); s[3] = (short)f2b(f0.w);
        s[4] = (short)f2b(f1.x); s[5] = (short)f2b(f1.y);
        s[6] = (short)f2b(f1.z); s[7] = (short)f2b(f1.w);
        a[ks] = s;
    }
    #pragma unroll
    for (int ct = 0; ct < 4; ct++) {
        floatx4 acc = {0.f, 0.f, 0.f, 0.f};
        #pragma unroll
        for (int ks = 0; ks < 4; ks++)
            acc = MFMA(a[ks], FRAG(Pg, ch * 4 + ct, ks, lane), acc);
        #pragma unroll
        for (int reg = 0; reg < 4; reg++)
            xs[(size_t)(rt * 16 + quad * 4 + reg) * 128 + (ch * 4 + ct) * 16 + m] =
                f2b(acc[reg]);
    }
}

// ---------------- GCN aggregation (unblocked; XCD-aligned rows) ------------
// h1[d] = relu(dinv_d*(sum_s dinv_s*xs[s] + dinv_d*xs[d]) + b)
// Row->XCD alignment (isolated this round): rows of partition p were
// col-written by XCD p during fill; bijective swizzle
// bid=(B&7)*(grid/8)+(B>>3) puts their agg blocks on the same XCD so
// col/cnt reads are L2-local (guard: grid%8==0).

__global__ __launch_bounds__(256) void agg_gcn_kernel(
    const unsigned short* __restrict__ X, const int* __restrict__ cnt,
    const int* __restrict__ col, const float* __restrict__ bias,
    unsigned short* __restrict__ Y, int N)
{
    int B = (int)blockIdx.x;
    int bid = ((gridDim.x & 7) == 0) ? (B & 7) * ((int)gridDim.x >> 3) + (B >> 3) : B;
    int w = bid * 4 + ((int)threadIdx.x >> 6);
    if (w >= N) return;
    int lane = threadIdx.x & 63;
    int g = lane >> 4, t = lane & 15;
    const uint4* Xq = (const uint4*)X;

    int deg = cnt[w];
    int n = deg < CAP ? deg : CAP;
    int beg = w * CAP, end = beg + n;

    float acc[8] = {0.f, 0.f, 0.f, 0.f, 0.f, 0.f, 0.f, 0.f};

    int e = beg + g;
    for (; e + 12 < end; e += 16) {
        int s0 = col[e];
        int s1 = col[e + 4];
        int s2 = col[e + 8];
        int s3 = col[e + 12];
        float sc0 = rsqrtf((float)(cnt[s0] + 1));
        float sc1 = rsqrtf((float)(cnt[s1] + 1));
        float sc2 = rsqrtf((float)(cnt[s2] + 1));
        float sc3 = rsqrtf((float)(cnt[s3] + 1));
        uint4 q0 = Xq[(size_t)s0 * 16 + t];
        uint4 q1 = Xq[(size_t)s1 * 16 + t];
        uint4 q2 = Xq[(size_t)s2 * 16 + t];
        uint4 q3 = Xq[(size_t)s3 * 16 + t];
        ACC_Q(q0, sc0);
        ACC_Q(q1, sc1);
        ACC_Q(q2, sc2);
        ACC_Q(q3, sc3);
    }
    for (; e < end; e += 4) {
        int s0 = col[e];
        float sc0 = rsqrtf((float)(cnt[s0] + 1));
        uint4 q0 = Xq[(size_t)s0 * 16 + t];
        ACC_Q(q0, sc0);
    }

    #pragma unroll
    for (int i = 0; i < 8; i++) {
        acc[i] += __shfl_xor(acc[i], 16);
        acc[i] += __shfl_xor(acc[i], 32);
    }
    if (g == 0) {
        float dw = rsqrtf((float)(deg + 1));
        uint4 q = Xq[(size_t)w * 16 + t];  // self loop
        ACC_Q(q, dw);
        float4 b0 = *(const float4*)(bias + t * 8);
        float4 b1 = *(const float4*)(bias + t * 8 + 4);
        float out[8];
        out[0] = fmaxf(fmaf(acc[0], dw, b0.x), 0.f);
        out[1] = fmaxf(fmaf(acc[1], dw, b0.y), 0.f);
        out[2] = fmaxf(fmaf(acc[2], dw, b0.z), 0.f);
        out[3] = fmaxf(fmaf(acc[3], dw, b0.w), 0.f);
        out[4] = fmaxf(fmaf(acc[4], dw, b1.x), 0.f);
        out[5] = fmaxf(fmaf(acc[5], dw, b1.y), 0.f);
        out[6] = fmaxf(fmaf(acc[6], dw, b1.z), 0.f);
        out[7] = fmaxf(fmaf(acc[7], dw, b1.w), 0.f);
        uint4 r;
        r.x = (unsigned)f2b(out[0]) | ((unsigned)f2b(out[1]) << 16);
        r.y = (unsigned)f2b(out[2]) | ((unsigned)f2b(out[3]) << 16);
        r.z = (unsigned)f2b(out[4]) | ((unsigned)f2b(out[5]) << 16);
        r.w = (unsigned)f2b(out[6]) | ((unsigned)f2b(out[7]) << 16);
        ((uint4*)Y)[(size_t)w * 16 + t] = r;
    }
}

// ---------------- fused SAGE-mean + SAGE layer + MLP + value head ----------
// One block per 16-row tile. Phase A: wave widx mean-aggregates rows
// widx*4..+3 of h1 into LDS zm (bf16), unblocked unroll-4 gather.
// Phase B: 4 waves cooperate on the tile's MLP (2 of 8 ct-tiles each per
// 128-col layer, 1 of 4 in layer 3), ping-ponging zm <-> za with barriers.

__global__ __launch_bounds__(256) void sage_fused_kernel(
    const unsigned short* __restrict__ h1, const int* __restrict__ cnt,
    const int* __restrict__ col,
    const unsigned short* __restrict__ Psl, const unsigned short* __restrict__ Psr,
    const float* __restrict__ bsl,
    const unsigned short* __restrict__ P1, const float* __restrict__ b1,
    const unsigned short* __restrict__ P2, const float* __restrict__ b2,
    const unsigned short* __restrict__ P3, const float* __restrict__ b3,
    const float* __restrict__ Wv, const float* __restrict__ bv,
    float* __restrict__ means, float* __restrict__ values, int N)
{
    __shared__ unsigned short zm[16 * 136];   // mean, later z1
    __shared__ unsigned short za[16 * 136];   // h2, later z2
    __shared__ float vp[16][4];               // value partials [row][wave]
    int widx = threadIdx.x >> 6, lane = threadIdx.x & 63;
    int r0 = blockIdx.x * 16;
    if (r0 >= N) return;
    int g = lane >> 4, t = lane & 15;
    const uint4* Xq = (const uint4*)h1;

    // ---- phase A: mean aggregation, wave widx -> rows widx*4 .. +3 ----
    for (int rr = 0; rr < 4; rr++) {
        int w = r0 + widx * 4 + rr;
        int deg = cnt[w];
        int n = deg < CAP ? deg : CAP;
        int beg = w * CAP, end = beg + n;
        float acc[8] = {0.f, 0.f, 0.f, 0.f, 0.f, 0.f, 0.f, 0.f};
        int e = beg + g;
        for (; e + 12 < end; e += 16) {
            int s0 = col[e];
            int s1 = col[e + 4];
            int s2 = col[e + 8];
            int s3 = col[e + 12];
            uint4 q0 = Xq[(size_t)s0 * 16 + t];
            uint4 q1 = Xq[(size_t)s1 * 16 + t];
            uint4 q2 = Xq[(size_t)s2 * 16 + t];
            uint4 q3 = Xq[(size_t)s3 * 16 + t];
            ACC_Q1(q0);
            ACC_Q1(q1);
            ACC_Q1(q2);
            ACC_Q1(q3);
        }
        for (; e < end; e += 4) {
            int s0 = col[e];
            uint4 q0 = Xq[(size_t)s0 * 16 + t];
            ACC_Q1(q0);
        }
        #pragma unroll
        for (int i = 0; i < 8; i++) {
            acc[i] += __shfl_xor(acc[i], 16);
            acc[i] += __shfl_xor(acc[i], 32);
        }
        if (g == 0) {
            float rc = 1.0f / (float)(deg > 0 ? deg : 1);
            uint4 r;
            r.x = (unsigned)f2b(acc[0] * rc) | ((unsigned)f2b(acc[1] * rc) << 16);
            r.y = (unsigned)f2b(acc[2] * rc) | ((unsigned)f2b(acc[3] * rc) << 16);
            r.z = (unsigned)f2b(acc[4] * rc) | ((unsigned)f2b(acc[5] * rc) << 16);
            r.w = (unsigned)f2b(acc[6] * rc) | ((unsigned)f2b(acc[7] * rc) << 16);
            *(uint4*)(zm + (widx * 4 + rr) * 136 + t * 8) = r;
        }
    }
    __syncthreads();   // B1: zm (mean) complete

    int m = t, quad = g;

    // A fragments: mean from LDS, root h1 from global
    short8 am[4], ar[4];
    #pragma unroll
    for (int ks = 0; ks < 4; ks++) {
        am[ks] = *(const short8*)(zm + m * 136 + ks * 32 + quad * 8);
        ar[ks] = *(const short8*)(h1 + (size_t)(r0 + m) * 128 + ks * 32 + quad * 8);
    }

    // SAGE layer: wave widx -> ct = 2*widx, 2*widx+1; h2 -> za; value partials
    float vpart[4] = {0.f, 0.f, 0.f, 0.f};
    #pragma unroll
    for (int ci = 0; ci < 2; ci++) {
        int ct = widx * 2 + ci;
        floatx4 acc = {0.f, 0.f, 0.f, 0.f};
        #pragma unroll
        for (int ks = 0; ks < 4; ks++) acc = MFMA(am[ks], FRAG(Psl, ct, ks, lane), acc);
        #pragma unroll
        for (int ks = 0; ks < 4; ks++) acc = MFMA(ar[ks], FRAG(Psr, ct, ks, lane), acc);
        float bb = bsl[ct * 16 + m];
        float wvv = Wv[ct * 16 + m];
        #pragma unroll
        for (int reg = 0; reg < 4; reg++) {
            float o = fmaxf(acc[reg] + bb, 0.f);
            vpart[reg] = fmaf(o, wvv, vpart[reg]);
            za[(quad * 4 + reg) * 136 + ct * 16 + m] = f2b(o);
        }
    }
    #pragma unroll
    for (int off = 1; off <= 8; off <<= 1) {
        #pragma unroll
        for (int reg = 0; reg < 4; reg++)
            vpart[reg] += __shfl_xor(vpart[reg], off);
    }
    if (m == 0) {
        #pragma unroll
        for (int reg = 0; reg < 4; reg++)
            vp[quad * 4 + reg][widx] = vpart[reg];
    }
    __syncthreads();   // B2: za (h2), vp complete

    if (threadIdx.x < 16) {
        float v = vp[threadIdx.x][0] + vp[threadIdx.x][1]
                + vp[threadIdx.x][2] + vp[threadIdx.x][3];
        values[r0 + threadIdx.x] = v + bv[0];
    }

    // layer 1: za -> zm
    short8 a1[4];
    #pragma unroll
    for (int ks = 0; ks < 4; ks++)
        a1[ks] = *(const short8*)(za + m * 136 + ks * 32 + quad * 8);
    #pragma unroll
    for (int ci = 0; ci < 2; ci++) {
        int ct = widx * 2 + ci;
        floatx4 acc = {0.f, 0.f, 0.f, 0.f};
        #pragma unroll
        for (int ks = 0; ks < 4; ks++) acc = MFMA(a1[ks], FRAG(P1, ct, ks, lane), acc);
        float bb = b1[ct * 16 + m];
        #pragma unroll
        for (int reg = 0; reg < 4; reg++)
            zm[(quad * 4 + reg) * 136 + ct * 16 + m] = f2b(gelu_exact(acc[reg] + bb));
    }
    __syncthreads();   // B3: zm (z1) complete

    // layer 2: zm -> za
    short8 a2[4];
    #pragma unroll
    for (int ks = 0; ks < 4; ks++)
        a2[ks] = *(const short8*)(zm + m * 136 + ks * 32 + quad * 8);
    #pragma unroll
    for (int ci = 0; ci < 2; ci++) {
        int ct = widx * 2 + ci;
        floatx4 acc = {0.f, 0.f, 0.f, 0.f};
        #pragma unroll
        for (int ks = 0; ks < 4; ks++) acc = MFMA(a2[ks], FRAG(P2, ct, ks, lane), acc);
        float bb = b2[ct * 16 + m];
        #pragma unroll
        for (int reg = 0; reg < 4; reg++)
            za[(quad * 4 + reg) * 136 + ct * 16 + m] = f2b(gelu_exact(acc[reg] + bb));
    }
    __syncthreads();   // B4: za (z2) complete

    // layer 3 (64 cols): wave widx -> ct = widx; za -> means (global)
    short8 a3[4];
    #pragma unroll
    for (int ks = 0; ks < 4; ks++)
        a3[ks] = *(const short8*)(za + m * 136 + ks * 32 + quad * 8);
    {
        int ct = widx;
        floatx4 acc = {0.f, 0.f, 0.f, 0.f};
        #pragma unroll
        for (int ks = 0; ks < 4; ks++) acc = MFMA(a3[ks], FRAG(P3, ct, ks, lane), acc);
        float bb = b3[ct * 16 + m];
        #pragma unroll
        for (int reg = 0; reg < 4; reg++)
            means[(size_t)(r0 + quad * 4 + reg) * 64 + ct * 16 + m] = acc[reg] + bb;
    }
}

// ---------------- launch ----------------

extern "C" void kernel_launch(void* const* d_in, const int* in_sizes, int n_in,
                              void* d_out, int out_size, void* d_ws, size_t ws_size,
                              hipStream_t stream) {
    const float* feat  = (const float*)d_in[0];
    const int*   eidx  = (const int*)d_in[1];
    const float* W_gcn = (const float*)d_in[2];
    const float* b_gcn = (const float*)d_in[3];
    const float* W_sl  = (const float*)d_in[4];
    const float* b_sl  = (const float*)d_in[5];
    const float* W_sr  = (const float*)d_in[6];
    const float* W1    = (const float*)d_in[7];
    const float* b1    = (const float*)d_in[8];
    const float* W2    = (const float*)d_in[9];
    const float* b2    = (const float*)d_in[10];
    const float* W3    = (const float*)d_in[11];
    const float* b3    = (const float*)d_in[12];
    const float* Wv    = (const float*)d_in[13];
    const float* bv    = (const float*)d_in[14];

    const int N = in_sizes[0] / 128;
    const int E = in_sizes[1] / 2;

    char* ws = (char*)d_ws;
    size_t off = 0;
    auto alloc = [&](size_t bytes) -> void* {
        void* p = ws + off;
        off += (bytes + 255) & ~(size_t)255;
        return p;
    };
    int*   cnt = (int*)alloc((size_t)N * 4);
    int*   col = (int*)alloc((size_t)N * CAP * 4);         // padded CSR, 7.68 MB
    unsigned short* xs   = (unsigned short*)alloc((size_t)N * 128 * 2);
    unsigned short* h1   = (unsigned short*)alloc((size_t)N * 128 * 2);
    unsigned short* Pg   = (unsigned short*)alloc(2048 * 8 * 2);
    unsigned short* Psl  = (unsigned short*)alloc(2048 * 8 * 2);
    unsigned short* Psr  = (unsigned short*)alloc(2048 * 8 * 2);
    unsigned short* P1   = (unsigned short*)alloc(2048 * 8 * 2);
    unsigned short* P2   = (unsigned short*)alloc(2048 * 8 * 2);
    unsigned short* P3   = (unsigned short*)alloc(1024 * 8 * 2);

    // 1: pack weights + zero cnt
    pack_zero_kernel<<<44, 256, 0, stream>>>(
        cnt, N, W_gcn, W_sl, W_sr, W1, W2, W3,
        Pg, Psl, Psr, P1, P2, P3);

    // 2: padded-CSR fill (one atomic pass, XCD-partitioned) + GCN GEMM
    const int PS = (N + 7) / 8;                            // 2500 rows / partition
    const int fillBlocks = ((E + 2047) / 2048) * 8;        // 313 chunks x 8 = 2504
    const int gemmBlocks = ((N / 16) * 2 + 3) / 4;         // 625
    fill_gemm_kernel<<<fillBlocks + gemmBlocks, 256, 0, stream>>>(
        eidx, E, cnt, col, feat, Pg, xs, N, fillBlocks, PS);

    // 3: GCN aggregation (unblocked, XCD-aligned rows)
    const int agrid = (N + 3) / 4;                         // 5000 (= 8*625)
    agg_gcn_kernel<<<agrid, 256, 0, stream>>>(xs, cnt, col, b_gcn, h1, N);

    // 4: fused SAGE mean + SAGE layer + MLP + value head
    sage_fused_kernel<<<(N + 15) / 16, 256, 0, stream>>>(
        h1, cnt, col, Psl, Psr, b_sl, P1, b1, P2, b2, P3, b3, Wv, bv,
        (float*)d_out, (float*)d_out + (size_t)N * 64, N);
}